// Round 11
// baseline (113.245 us; speedup 1.0000x reference)
//
#include <hip/hip_runtime.h>
#include <cstdint>

typedef __attribute__((ext_vector_type(8)))  short short8;
typedef __attribute__((ext_vector_type(16))) float floatx16;

constexpr int NB = 4;        // batch
constexpr int NV = 8192;     // vertices
constexpr int NF = 16384;    // faces
constexpr int NP = 8192;     // query points per batch
constexpr float F_EPS = 1e-3f;
constexpr float F_WEIGHT = 1000.0f;
constexpr float BIAS = 1e-3f;        // keeps dist^2 > 0 despite bf16 rounding

constexpr int PT_TILES = NP / 32;        // 256 point tiles (32-wide) / batch
constexpr int FC_TILES = NF / 32;        // 512 face tiles (32-wide) / batch
constexpr int TPB = 256;                 // 4 waves
constexpr int FS = 16;                   // face slices
constexpr int SL_TILES = FC_TILES / FS;  // 32 face tiles (1024 faces) / slice
constexpr int CH = 16;                   // face tiles per LDS chunk (16 KB)
constexpr int NCHUNK = SL_TILES / CH;    // 2
constexpr int PGB = 64;                  // point groups (128 pts) / batch
// grid = PGB x FS x NB = 4096 blocks = 16/CU oversubscribed

union FragU { uint4 u; short8 s; };

__device__ inline unsigned f2bf(float f) {           // fp32 -> bf16 (RNE)
    unsigned u = __float_as_uint(f);
    return (u + 0x7FFFu + ((u >> 16) & 1u)) >> 16;
}
__device__ inline float bf2f(unsigned h) { return __uint_as_float(h << 16); }
__device__ inline unsigned pk(unsigned lo, unsigned hi) {
    return (lo & 0xFFFFu) | (hi << 16);
}

// ---------------------------------------------------------------------------
// Fused prep. 32x32x16 MFMA, K=16 fully used. Lane L of an operand tile holds
// elem[idx = L&31][k = (L>>5)*8 + j], j=0..7. K-slot maps:
//  A (point m): k0..2=-2p_hi k3..5=-2p_lo k6..8=-2p_hi k9..11=-2p_lo
//               k12=1 k13=1 k14=p2b_hi k15=p2b_lo
//  B (face n):  k0..5=c_hi,c_hi  k6..11=c_lo,c_lo  k12=c2_hi k13=c2_lo k14=1 k15=1
//  => D[m][n] = p2b[m] + c2[n] - 2 p.c = dist^2 + BIAS > 0
// Also inits keys (0xFF), acc (0), ticket (0) -- no separate memsets.
// ---------------------------------------------------------------------------
__global__ void prep_kernel(const float* __restrict__ pred,
                            const float* __restrict__ pos,
                            const int*   __restrict__ faces,
                            uint4* __restrict__ a_frags,
                            uint4* __restrict__ b_frags,
                            float4* __restrict__ centers4,
                            float4* __restrict__ normals4,
                            unsigned* __restrict__ keys,
                            float* __restrict__ acc,
                            unsigned* __restrict__ tk) {
    int i = blockIdx.x * blockDim.x + threadIdx.x;   // [0, NB*NF)
    if (i >= NB * NF) return;
    if (i < 2) acc[i] = 0.0f;
    if (i == 0) tk[0] = 0u;

    const unsigned ONE = 0x3F80u;

    // ---- faces ----
    {
        int b = i / NF, f = i & (NF - 1);
        const float* p = pos + (size_t)b * NV * 3;
        int i0 = faces[3 * (size_t)i], i1 = faces[3 * (size_t)i + 1], i2 = faces[3 * (size_t)i + 2];
        float ax = p[3 * i0], ay = p[3 * i0 + 1], az = p[3 * i0 + 2];
        float bx = p[3 * i1], by = p[3 * i1 + 1], bz = p[3 * i1 + 2];
        float cx = p[3 * i2], cy = p[3 * i2 + 1], cz = p[3 * i2 + 2];

        const float third = 1.0f / 3.0f;
        float mx = (ax + bx + cx) * third;
        float my = (ay + by + cy) * third;
        float mz = (az + bz + cz) * third;
        float c2 = mx * mx + my * my + mz * mz;

        float e1x = bx - ax, e1y = by - ay, e1z = bz - az;
        float e2x = cx - ax, e2y = cy - ay, e2z = cz - az;
        float nx = e1y * e2z - e1z * e2y;
        float ny = e1z * e2x - e1x * e2z;
        float nz = e1x * e2y - e1y * e2x;
        float len = sqrtf(nx * nx + ny * ny + nz * nz);
        float inv = 1.0f / fmaxf(len, 1e-12f);

        centers4[i] = make_float4(mx, my, mz, c2);
        normals4[i] = make_float4(nx * inv, ny * inv, nz * inv, 0.0f);

        unsigned bhx = f2bf(mx), bhy = f2bf(my), bhz = f2bf(mz);
        unsigned blx = f2bf(mx - bf2f(bhx)), bly = f2bf(my - bf2f(bhy)), blz = f2bf(mz - bf2f(bhz));
        unsigned c2h = f2bf(c2);
        unsigned c2l = f2bf(c2 - bf2f(c2h));

        int tile = f >> 5, n = f & 31;
        uint4* bb = b_frags + (size_t)(b * FC_TILES + tile) * 64;
        bb[n]      = make_uint4(pk(bhx, bhy), pk(bhz, bhx), pk(bhy, bhz), pk(blx, bly)); // k0..7
        bb[32 + n] = make_uint4(pk(blz, blx), pk(bly, blz), pk(c2h, c2l), pk(ONE, ONE)); // k8..15
    }

    // ---- points ----
    if (i < NB * NP) {
        keys[i] = 0xFFFFFFFFu;
        int pb = i / NP, pn = i & (NP - 1);
        float x = pred[3 * (size_t)i], y = pred[3 * (size_t)i + 1], z = pred[3 * (size_t)i + 2];
        unsigned hx = f2bf(x), hy = f2bf(y), hz = f2bf(z);
        float rx = x - bf2f(hx), ry = y - bf2f(hy), rz = z - bf2f(hz);
        unsigned ahx = f2bf(-2.f * bf2f(hx)), ahy = f2bf(-2.f * bf2f(hy)), ahz = f2bf(-2.f * bf2f(hz));
        unsigned alx = f2bf(-2.f * rx), aly = f2bf(-2.f * ry), alz = f2bf(-2.f * rz);
        float p2 = x * x + y * y + z * z + BIAS;
        unsigned p2h = f2bf(p2);
        unsigned p2l = f2bf(p2 - bf2f(p2h));

        int tile = pn >> 5, m = pn & 31;
        uint4* ab = a_frags + (size_t)(pb * PT_TILES + tile) * 64;
        ab[m]      = make_uint4(pk(ahx, ahy), pk(ahz, alx), pk(aly, alz), pk(ahx, ahy)); // k0..7
        ab[32 + m] = make_uint4(pk(ahz, alx), pk(aly, alz), pk(ONE, ONE), pk(p2h, p2l)); // k8..15
    }
}

// ---------------------------------------------------------------------------
// 1-NN on the matrix pipe: asm 32x32x16 MFMA, ALL operands in arch VGPRs
// ("=&v" D, "v" C -- gfx950 requires C and D in the same register file;
// r10's AGPR-C + VGPR-D mix does not assemble). ONE A-tile per wave keeps
// the footprint ~85 arch VGPRs -> ~5 waves/SIMD (r9 had 2 at 49% idle).
// Block = (128 points, 1024-face slice, batch); tile-pairing keeps the
// epilogue at 1.5 instr/elem (and_or x2 + min3 per 2 elems).
// C/D layout (verified r4-r9, absmax 0.0):
//   col(face) = lane&31, row(point) = (reg&3) + 8*(reg>>2) + 4*(lane>>5).
// key = (bits(dist^2+BIAS) & 0xFFFFC000) | face_idx; cross-slice atomicMin.
// ---------------------------------------------------------------------------
__global__ __launch_bounds__(TPB) void nn_kernel(
        const uint4* __restrict__ a_frags,
        const uint4* __restrict__ b_frags,
        unsigned* __restrict__ keys) {
    const int pg = blockIdx.x, sl = blockIdx.y, b = blockIdx.z;
    const int tid = threadIdx.x, wave = tid >> 6, lane = tid & 63;

    __shared__ uint4 sb[CH * 64];        // 16 KB

    // one 32-point A-tile per wave
    const int pt_tile = pg * 4 + wave;
    FragU a;
    a.u = a_frags[((size_t)(b * PT_TILES + pt_tile)) * 64 + lane];

    unsigned best[16];
#pragma unroll
    for (int e = 0; e < 16; ++e) best[e] = 0xFFFFFFFFu;

    const floatx16 zero = {0.f, 0.f, 0.f, 0.f, 0.f, 0.f, 0.f, 0.f,
                           0.f, 0.f, 0.f, 0.f, 0.f, 0.f, 0.f, 0.f};
    const uint4* bp = b_frags + ((size_t)(b * FC_TILES + sl * SL_TILES)) * 64;

    for (int ch = 0; ch < NCHUNK; ++ch) {
        const uint4* gsrc = bp + (size_t)ch * CH * 64;
        __syncthreads();                 // previous chunk fully consumed
#pragma unroll
        for (int k = 0; k < (CH * 64) / TPB; ++k)
            sb[k * TPB + tid] = gsrc[k * TPB + tid];
        __syncthreads();

        unsigned vf = (unsigned)((sl * SL_TILES + ch * CH) * 32 + (lane & 31));
#pragma unroll
        for (int t = 0; t < CH; t += 2) {
            FragU fb0, fb1;
            fb0.u = sb[t * 64 + lane];
            fb1.u = sb[t * 64 + 64 + lane];
            floatx16 d0, d1;
            // "=&v": earlyclobber arch-VGPR dsts, disjoint from all inputs.
            // Hazard cover for first d0 read: 2nd MFMA issue (~8cyc) +
            // 2x s_nop 7 (16cyc); d1 first read is behind d0's epilogue.
            asm("v_mfma_f32_32x32x16_bf16 %0, %2, %3, %5\n\t"
                "v_mfma_f32_32x32x16_bf16 %1, %2, %4, %5\n\t"
                "s_nop 7\n\t"
                "s_nop 7"
                : "=&v"(d0), "=&v"(d1)
                : "v"(a.s), "v"(fb0.s), "v"(fb1.s), "v"(zero));
#pragma unroll
            for (int r = 0; r < 16; ++r) {
                unsigned k0 = (__float_as_uint(d0[r]) & 0xFFFFC000u) | vf;
                unsigned k1 = (__float_as_uint(d1[r]) & 0xFFFFC000u) | (vf + 32u);
                best[r] = min(best[r], min(k0, k1));     // -> v_min3_u32
            }
            vf += 64u;
        }
    }

    // min across the 32 face-columns (stays within each 32-lane half)
#pragma unroll
    for (int e = 0; e < 16; ++e) {
        unsigned v = best[e];
#pragma unroll
        for (int m = 1; m < 32; m <<= 1)
            v = min(v, (unsigned)__shfl_xor((int)v, m, 64));
        best[e] = v;
    }
    unsigned* kb = keys + b * NP;
    if ((lane & 31) == 0) {
        int half = lane >> 5;
#pragma unroll
        for (int r = 0; r < 16; ++r) {
            int row = (r & 3) + 8 * (r >> 2) + 4 * half;
            atomicMin(&kb[pt_tile * 32 + row], best[r]);
        }
    }
}

// ---------------------------------------------------------------------------
// Per-point signed plane distance -> interp^3 sum + hit count; the LAST of
// the 128 blocks (device ticket) writes d_out. Fence cost is trivial here.
// ---------------------------------------------------------------------------
__global__ __launch_bounds__(TPB) void finalize_kernel(
        const float* __restrict__ pred,
        const float4* __restrict__ centers4,
        const float4* __restrict__ normals4,
        const unsigned int* __restrict__ keys,
        float* __restrict__ acc,
        unsigned* __restrict__ tk,
        float* __restrict__ out,
        int nblocks) {
    int i = blockIdx.x * blockDim.x + threadIdx.x;   // 0 .. B*N-1
    float val = 0.0f, cnt = 0.0f;
    if (i < NB * NP) {
        int b = i / NP;
        unsigned key = keys[i];
        int idx = (int)(key & (unsigned)(NF - 1));
        float4 c  = centers4[b * NF + idx];
        float4 nr = normals4[b * NF + idx];
        const float* pp = pred + (size_t)i * 3;
        float dx = pp[0] - c.x, dy = pp[1] - c.y, dz = pp[2] - c.z;
        float dist = dx * nr.x + dy * nr.y + dz * nr.z;
        float t = F_EPS - dist;
        if (t > 0.0f) { cnt = 1.0f; val = t * t * t; }
    }
    for (int off = 32; off > 0; off >>= 1) {
        val += __shfl_down(val, off, 64);
        cnt += __shfl_down(cnt, off, 64);
    }
    __shared__ float sv[TPB / 64], sn[TPB / 64];
    __shared__ unsigned s_tkt;
    int lane = threadIdx.x & 63, wave = threadIdx.x >> 6;
    if (lane == 0) { sv[wave] = val; sn[wave] = cnt; }
    __syncthreads();
    if (threadIdx.x == 0) {
        float v = 0.0f, cc = 0.0f;
#pragma unroll
        for (int w = 0; w < TPB / 64; ++w) { v += sv[w]; cc += sn[w]; }
        atomicAdd(&acc[0], v);
        atomicAdd(&acc[1], cc);
        __threadfence();
        s_tkt = atomicAdd(&tk[0], 1u);
        if (s_tkt == (unsigned)(nblocks - 1)) {      // last block writes out
            float a0 = __hip_atomic_load(&acc[0], __ATOMIC_RELAXED, __HIP_MEMORY_SCOPE_AGENT);
            float a1 = __hip_atomic_load(&acc[1], __ATOMIC_RELAXED, __HIP_MEMORY_SCOPE_AGENT);
            out[0] = a0 * (F_WEIGHT / (float)NB);
            out[1] = a1 * (1.0f / (float)(NB * NP));
        }
    }
}

extern "C" void kernel_launch(void* const* d_in, const int* in_sizes, int n_in,
                              void* d_out, int out_size, void* d_ws, size_t ws_size,
                              hipStream_t stream) {
    const float* pred  = (const float*)d_in[0];   // [B,N,3] f32
    const float* opos  = (const float*)d_in[1];   // [B,V,3] f32
    const int*   faces = (const int*)  d_in[2];   // [B,F,3] i32

    char* ws = (char*)d_ws;
    const size_t a_bytes = (size_t)NB * PT_TILES * 64 * 16;   // 1 MiB
    const size_t b_bytes = (size_t)NB * FC_TILES * 64 * 16;   // 2 MiB
    const size_t c_bytes = (size_t)NB * NF * 16;              // 1 MiB
    const size_t k_bytes = (size_t)NB * NP * sizeof(unsigned);// 128 KiB

    uint4*    a_frags  = (uint4*)ws;
    uint4*    b_frags  = (uint4*)(ws + a_bytes);
    float4*   centers4 = (float4*)(ws + a_bytes + b_bytes);
    float4*   normals4 = (float4*)(ws + a_bytes + b_bytes + c_bytes);
    unsigned* keys     = (unsigned*)(ws + a_bytes + b_bytes + 2 * c_bytes);
    float*    acc      = (float*)(ws + a_bytes + b_bytes + 2 * c_bytes + k_bytes);
    unsigned* tk       = (unsigned*)(ws + a_bytes + b_bytes + 2 * c_bytes + k_bytes + 64);

    prep_kernel<<<(NB * NF + TPB - 1) / TPB, TPB, 0, stream>>>(
        pred, opos, faces, a_frags, b_frags, centers4, normals4, keys, acc, tk);

    nn_kernel<<<dim3(PGB, FS, NB), TPB, 0, stream>>>(a_frags, b_frags, keys);

    int fin_blocks = (NB * NP + TPB - 1) / TPB;
    finalize_kernel<<<fin_blocks, TPB, 0, stream>>>(
        pred, centers4, normals4, keys, acc, tk, (float*)d_out, fin_blocks);
}

// Round 12
// 108.370 us; speedup vs baseline: 1.0450x; 1.0450x over previous
//
#include <hip/hip_runtime.h>
#include <cstdint>

typedef __attribute__((ext_vector_type(8)))  short short8;
typedef __attribute__((ext_vector_type(16))) float floatx16;

constexpr int NB = 4;        // batch
constexpr int NV = 8192;     // vertices
constexpr int NF = 16384;    // faces
constexpr int NP = 8192;     // query points per batch
constexpr float F_EPS = 1e-3f;
constexpr float F_WEIGHT = 1000.0f;
constexpr float BIAS = 1e-3f;        // keeps dist^2 > 0 despite bf16 rounding

constexpr int PT_TILES = NP / 32;        // 256 point tiles (32-wide) / batch
constexpr int FC_TILES = NF / 32;        // 512 face tiles (32-wide) / batch
constexpr int TPB = 256;                 // 4 waves
constexpr int FS = 16;                   // face slices
constexpr int SL_TILES = FC_TILES / FS;  // 32 face tiles (1024 faces) / slice
constexpr int CH = 16;                   // face tiles per LDS chunk (16 KB)
constexpr int NCHUNK = SL_TILES / CH;    // 2
constexpr int PGB = 64;                  // point groups (128 pts) / batch
// grid = PGB x FS x NB = 4096 blocks

union FragU { uint4 u; short8 s; };

__device__ inline unsigned f2bf(float f) {           // fp32 -> bf16 (RNE)
    unsigned u = __float_as_uint(f);
    return (u + 0x7FFFu + ((u >> 16) & 1u)) >> 16;
}
__device__ inline float bf2f(unsigned h) { return __uint_as_float(h << 16); }
__device__ inline unsigned pk(unsigned lo, unsigned hi) {
    return (lo & 0xFFFFu) | (hi << 16);
}

// ---------------------------------------------------------------------------
// Fused prep. 32x32x16 MFMA, K=16 fully used. Lane L of an operand tile holds
// elem[idx = L&31][k = (L>>5)*8 + j], j=0..7. K-slot maps:
//  A (point m): k0..2=-2p_hi k3..5=-2p_lo k6..8=-2p_hi k9..11=-2p_lo
//               k12=1 k13=1 k14=p2b_hi k15=p2b_lo
//  B (face n):  k0..5=c_hi,c_hi  k6..11=c_lo,c_lo  k12=c2_hi k13=c2_lo k14=1 k15=1
//  => D[m][n] = p2b[m] + c2[n] - 2 p.c = dist^2 + BIAS > 0
// Also inits keys (0xFF), acc (0), ticket (0) -- no separate memsets.
// ---------------------------------------------------------------------------
__global__ void prep_kernel(const float* __restrict__ pred,
                            const float* __restrict__ pos,
                            const int*   __restrict__ faces,
                            uint4* __restrict__ a_frags,
                            uint4* __restrict__ b_frags,
                            float4* __restrict__ centers4,
                            float4* __restrict__ normals4,
                            unsigned* __restrict__ keys,
                            float* __restrict__ acc,
                            unsigned* __restrict__ tk) {
    int i = blockIdx.x * blockDim.x + threadIdx.x;   // [0, NB*NF)
    if (i >= NB * NF) return;
    if (i < 2) acc[i] = 0.0f;
    if (i == 0) tk[0] = 0u;

    const unsigned ONE = 0x3F80u;

    // ---- faces ----
    {
        int b = i / NF, f = i & (NF - 1);
        const float* p = pos + (size_t)b * NV * 3;
        int i0 = faces[3 * (size_t)i], i1 = faces[3 * (size_t)i + 1], i2 = faces[3 * (size_t)i + 2];
        float ax = p[3 * i0], ay = p[3 * i0 + 1], az = p[3 * i0 + 2];
        float bx = p[3 * i1], by = p[3 * i1 + 1], bz = p[3 * i1 + 2];
        float cx = p[3 * i2], cy = p[3 * i2 + 1], cz = p[3 * i2 + 2];

        const float third = 1.0f / 3.0f;
        float mx = (ax + bx + cx) * third;
        float my = (ay + by + cy) * third;
        float mz = (az + bz + cz) * third;
        float c2 = mx * mx + my * my + mz * mz;

        float e1x = bx - ax, e1y = by - ay, e1z = bz - az;
        float e2x = cx - ax, e2y = cy - ay, e2z = cz - az;
        float nx = e1y * e2z - e1z * e2y;
        float ny = e1z * e2x - e1x * e2z;
        float nz = e1x * e2y - e1y * e2x;
        float len = sqrtf(nx * nx + ny * ny + nz * nz);
        float inv = 1.0f / fmaxf(len, 1e-12f);

        centers4[i] = make_float4(mx, my, mz, c2);
        normals4[i] = make_float4(nx * inv, ny * inv, nz * inv, 0.0f);

        unsigned bhx = f2bf(mx), bhy = f2bf(my), bhz = f2bf(mz);
        unsigned blx = f2bf(mx - bf2f(bhx)), bly = f2bf(my - bf2f(bhy)), blz = f2bf(mz - bf2f(bhz));
        unsigned c2h = f2bf(c2);
        unsigned c2l = f2bf(c2 - bf2f(c2h));

        int tile = f >> 5, n = f & 31;
        uint4* bb = b_frags + (size_t)(b * FC_TILES + tile) * 64;
        bb[n]      = make_uint4(pk(bhx, bhy), pk(bhz, bhx), pk(bhy, bhz), pk(blx, bly)); // k0..7
        bb[32 + n] = make_uint4(pk(blz, blx), pk(bly, blz), pk(c2h, c2l), pk(ONE, ONE)); // k8..15
    }

    // ---- points ----
    if (i < NB * NP) {
        keys[i] = 0xFFFFFFFFu;
        int pb = i / NP, pn = i & (NP - 1);
        float x = pred[3 * (size_t)i], y = pred[3 * (size_t)i + 1], z = pred[3 * (size_t)i + 2];
        unsigned hx = f2bf(x), hy = f2bf(y), hz = f2bf(z);
        float rx = x - bf2f(hx), ry = y - bf2f(hy), rz = z - bf2f(hz);
        unsigned ahx = f2bf(-2.f * bf2f(hx)), ahy = f2bf(-2.f * bf2f(hy)), ahz = f2bf(-2.f * bf2f(hz));
        unsigned alx = f2bf(-2.f * rx), aly = f2bf(-2.f * ry), alz = f2bf(-2.f * rz);
        float p2 = x * x + y * y + z * z + BIAS;
        unsigned p2h = f2bf(p2);
        unsigned p2l = f2bf(p2 - bf2f(p2h));

        int tile = pn >> 5, m = pn & 31;
        uint4* ab = a_frags + (size_t)(pb * PT_TILES + tile) * 64;
        ab[m]      = make_uint4(pk(ahx, ahy), pk(ahz, alx), pk(aly, alz), pk(ahx, ahy)); // k0..7
        ab[32 + m] = make_uint4(pk(ahz, alx), pk(aly, alz), pk(ONE, ONE), pk(p2h, p2l)); // k8..15
    }
}

// ---------------------------------------------------------------------------
// 1-NN on the matrix pipe. EVERY hot instruction is now single-instr inline
// asm: r6-r11 showed the compiler never forms v_and_or_b32/v_min3_u32 around
// asm-produced MFMA results (measured 3-4 VALU instr/elem vs the 1.5 floor;
// VALU-busy 24-42us vs 10.2us ideal). Epilogue per 2 elems:
//   v_and_or_b32 k0, d0[r], s_mask, vf      (VOP3: mask must be SGPR)
//   v_and_or_b32 k1, d1[r], s_mask, vf32
//   v_min3_u32  best[r], best[r], k0, k1
// MFMA pair in one asm block; 3x s_nop 7 (24cyc) covers the MFMA->VALU RAW
// hazard for both d0 (first read +24cyc) and d1 (+26cyc, needs ~25).
// One A-tile/wave (~100 VGPR -> ~5 waves/SIMD). C/D layout verified r4-r11:
//   col(face) = lane&31, row(point) = (reg&3) + 8*(reg>>2) + 4*(lane>>5).
// key = (bits(dist^2+BIAS) & 0xFFFFC000) | face_idx; cross-slice atomicMin.
// ---------------------------------------------------------------------------
__global__ __launch_bounds__(TPB) void nn_kernel(
        const uint4* __restrict__ a_frags,
        const uint4* __restrict__ b_frags,
        unsigned* __restrict__ keys) {
    const int pg = blockIdx.x, sl = blockIdx.y, b = blockIdx.z;
    const int tid = threadIdx.x, wave = tid >> 6, lane = tid & 63;

    __shared__ uint4 sb[CH * 64];        // 16 KB

    // one 32-point A-tile per wave
    const int pt_tile = pg * 4 + wave;
    FragU a;
    a.u = a_frags[((size_t)(b * PT_TILES + pt_tile)) * 64 + lane];

    unsigned best[16];
#pragma unroll
    for (int e = 0; e < 16; ++e) best[e] = 0xFFFFFFFFu;

    const floatx16 zero = {0.f, 0.f, 0.f, 0.f, 0.f, 0.f, 0.f, 0.f,
                           0.f, 0.f, 0.f, 0.f, 0.f, 0.f, 0.f, 0.f};
    const unsigned mask = 0xFFFFC000u;
    const uint4* bp = b_frags + ((size_t)(b * FC_TILES + sl * SL_TILES)) * 64;

    for (int ch = 0; ch < NCHUNK; ++ch) {
        const uint4* gsrc = bp + (size_t)ch * CH * 64;
        __syncthreads();                 // previous chunk fully consumed
#pragma unroll
        for (int k = 0; k < (CH * 64) / TPB; ++k)
            sb[k * TPB + tid] = gsrc[k * TPB + tid];
        __syncthreads();

        unsigned vf = (unsigned)((sl * SL_TILES + ch * CH) * 32 + (lane & 31));
#pragma unroll
        for (int t = 0; t < CH; t += 2) {
            FragU fb0, fb1;
            fb0.u = sb[t * 64 + lane];
            fb1.u = sb[t * 64 + 64 + lane];
            unsigned vf32 = vf + 32u;
            floatx16 d0, d1;
            asm("v_mfma_f32_32x32x16_bf16 %0, %2, %3, %5\n\t"
                "v_mfma_f32_32x32x16_bf16 %1, %2, %4, %5\n\t"
                "s_nop 7\n\t"
                "s_nop 7\n\t"
                "s_nop 7"
                : "=&v"(d0), "=&v"(d1)
                : "v"(a.s), "v"(fb0.s), "v"(fb1.s), "v"(zero));
#pragma unroll
            for (int r = 0; r < 16; ++r) {
                unsigned k0, k1;
                asm("v_and_or_b32 %0, %1, %2, %3"
                    : "=v"(k0) : "v"(d0[r]), "s"(mask), "v"(vf));
                asm("v_and_or_b32 %0, %1, %2, %3"
                    : "=v"(k1) : "v"(d1[r]), "s"(mask), "v"(vf32));
                asm("v_min3_u32 %0, %0, %1, %2"
                    : "+v"(best[r]) : "v"(k0), "v"(k1));
            }
            vf += 64u;
        }
    }

    // min across the 32 face-columns (stays within each 32-lane half)
#pragma unroll
    for (int e = 0; e < 16; ++e) {
        unsigned v = best[e];
#pragma unroll
        for (int m = 1; m < 32; m <<= 1)
            v = min(v, (unsigned)__shfl_xor((int)v, m, 64));
        best[e] = v;
    }
    unsigned* kb = keys + b * NP;
    if ((lane & 31) == 0) {
        int half = lane >> 5;
#pragma unroll
        for (int r = 0; r < 16; ++r) {
            int row = (r & 3) + 8 * (r >> 2) + 4 * half;
            atomicMin(&kb[pt_tile * 32 + row], best[r]);
        }
    }
}

// ---------------------------------------------------------------------------
// Per-point signed plane distance -> interp^3 sum + hit count; the LAST of
// the 128 blocks (device ticket) writes d_out. Fence cost is trivial here.
// ---------------------------------------------------------------------------
__global__ __launch_bounds__(TPB) void finalize_kernel(
        const float* __restrict__ pred,
        const float4* __restrict__ centers4,
        const float4* __restrict__ normals4,
        const unsigned int* __restrict__ keys,
        float* __restrict__ acc,
        unsigned* __restrict__ tk,
        float* __restrict__ out,
        int nblocks) {
    int i = blockIdx.x * blockDim.x + threadIdx.x;   // 0 .. B*N-1
    float val = 0.0f, cnt = 0.0f;
    if (i < NB * NP) {
        int b = i / NP;
        unsigned key = keys[i];
        int idx = (int)(key & (unsigned)(NF - 1));
        float4 c  = centers4[b * NF + idx];
        float4 nr = normals4[b * NF + idx];
        const float* pp = pred + (size_t)i * 3;
        float dx = pp[0] - c.x, dy = pp[1] - c.y, dz = pp[2] - c.z;
        float dist = dx * nr.x + dy * nr.y + dz * nr.z;
        float t = F_EPS - dist;
        if (t > 0.0f) { cnt = 1.0f; val = t * t * t; }
    }
    for (int off = 32; off > 0; off >>= 1) {
        val += __shfl_down(val, off, 64);
        cnt += __shfl_down(cnt, off, 64);
    }
    __shared__ float sv[TPB / 64], sn[TPB / 64];
    __shared__ unsigned s_tkt;
    int lane = threadIdx.x & 63, wave = threadIdx.x >> 6;
    if (lane == 0) { sv[wave] = val; sn[wave] = cnt; }
    __syncthreads();
    if (threadIdx.x == 0) {
        float v = 0.0f, cc = 0.0f;
#pragma unroll
        for (int w = 0; w < TPB / 64; ++w) { v += sv[w]; cc += sn[w]; }
        atomicAdd(&acc[0], v);
        atomicAdd(&acc[1], cc);
        __threadfence();
        s_tkt = atomicAdd(&tk[0], 1u);
        if (s_tkt == (unsigned)(nblocks - 1)) {      // last block writes out
            float a0 = __hip_atomic_load(&acc[0], __ATOMIC_RELAXED, __HIP_MEMORY_SCOPE_AGENT);
            float a1 = __hip_atomic_load(&acc[1], __ATOMIC_RELAXED, __HIP_MEMORY_SCOPE_AGENT);
            out[0] = a0 * (F_WEIGHT / (float)NB);
            out[1] = a1 * (1.0f / (float)(NB * NP));
        }
    }
}

extern "C" void kernel_launch(void* const* d_in, const int* in_sizes, int n_in,
                              void* d_out, int out_size, void* d_ws, size_t ws_size,
                              hipStream_t stream) {
    const float* pred  = (const float*)d_in[0];   // [B,N,3] f32
    const float* opos  = (const float*)d_in[1];   // [B,V,3] f32
    const int*   faces = (const int*)  d_in[2];   // [B,F,3] i32

    char* ws = (char*)d_ws;
    const size_t a_bytes = (size_t)NB * PT_TILES * 64 * 16;   // 1 MiB
    const size_t b_bytes = (size_t)NB * FC_TILES * 64 * 16;   // 2 MiB
    const size_t c_bytes = (size_t)NB * NF * 16;              // 1 MiB
    const size_t k_bytes = (size_t)NB * NP * sizeof(unsigned);// 128 KiB

    uint4*    a_frags  = (uint4*)ws;
    uint4*    b_frags  = (uint4*)(ws + a_bytes);
    float4*   centers4 = (float4*)(ws + a_bytes + b_bytes);
    float4*   normals4 = (float4*)(ws + a_bytes + b_bytes + c_bytes);
    unsigned* keys     = (unsigned*)(ws + a_bytes + b_bytes + 2 * c_bytes);
    float*    acc      = (float*)(ws + a_bytes + b_bytes + 2 * c_bytes + k_bytes);
    unsigned* tk       = (unsigned*)(ws + a_bytes + b_bytes + 2 * c_bytes + k_bytes + 64);

    prep_kernel<<<(NB * NF + TPB - 1) / TPB, TPB, 0, stream>>>(
        pred, opos, faces, a_frags, b_frags, centers4, normals4, keys, acc, tk);

    nn_kernel<<<dim3(PGB, FS, NB), TPB, 0, stream>>>(a_frags, b_frags, keys);

    int fin_blocks = (NB * NP + TPB - 1) / TPB;
    finalize_kernel<<<fin_blocks, TPB, 0, stream>>>(
        pred, centers4, normals4, keys, acc, tk, (float*)d_out, fin_blocks);
}

// Round 13
// 105.454 us; speedup vs baseline: 1.0739x; 1.0277x over previous
//
#include <hip/hip_runtime.h>
#include <cstdint>

typedef __attribute__((ext_vector_type(8)))  short short8;
typedef __attribute__((ext_vector_type(16))) float floatx16;

constexpr int NB = 4;        // batch
constexpr int NV = 8192;     // vertices
constexpr int NF = 16384;    // faces
constexpr int NP = 8192;     // query points per batch
constexpr float F_EPS = 1e-3f;
constexpr float F_WEIGHT = 1000.0f;
constexpr float BIAS = 1e-3f;        // keeps dist^2 > 0 despite bf16 rounding

constexpr int PT_TILES = NP / 32;        // 256 point tiles (32-wide) / batch
constexpr int FC_TILES = NF / 32;        // 512 face tiles (32-wide) / batch
constexpr int TPB = 256;                 // 4 waves
constexpr int FS = 16;                   // face slices
constexpr int SL_TILES = FC_TILES / FS;  // 32 face tiles (1024 faces) / slice -> 32KB LDS
constexpr int PGB = 64;                  // point groups (128 pts) / batch
// grid = PGB x FS x NB = 4096 blocks

union FragU { uint4 u; short8 s; };

__device__ inline unsigned f2bf(float f) {           // fp32 -> bf16 (RNE)
    unsigned u = __float_as_uint(f);
    return (u + 0x7FFFu + ((u >> 16) & 1u)) >> 16;
}
__device__ inline float bf2f(unsigned h) { return __uint_as_float(h << 16); }
__device__ inline unsigned pk(unsigned lo, unsigned hi) {
    return (lo & 0xFFFFu) | (hi << 16);
}

// ---------------------------------------------------------------------------
// Fused prep (unchanged from r12; verified absmax 0.0 through r6-r12).
// ---------------------------------------------------------------------------
__global__ void prep_kernel(const float* __restrict__ pred,
                            const float* __restrict__ pos,
                            const int*   __restrict__ faces,
                            uint4* __restrict__ a_frags,
                            uint4* __restrict__ b_frags,
                            float4* __restrict__ centers4,
                            float4* __restrict__ normals4,
                            unsigned* __restrict__ keys,
                            float* __restrict__ acc,
                            unsigned* __restrict__ tk) {
    int i = blockIdx.x * blockDim.x + threadIdx.x;   // [0, NB*NF)
    if (i >= NB * NF) return;
    if (i < 2) acc[i] = 0.0f;
    if (i == 0) tk[0] = 0u;

    const unsigned ONE = 0x3F80u;

    // ---- faces ----
    {
        int b = i / NF, f = i & (NF - 1);
        const float* p = pos + (size_t)b * NV * 3;
        int i0 = faces[3 * (size_t)i], i1 = faces[3 * (size_t)i + 1], i2 = faces[3 * (size_t)i + 2];
        float ax = p[3 * i0], ay = p[3 * i0 + 1], az = p[3 * i0 + 2];
        float bx = p[3 * i1], by = p[3 * i1 + 1], bz = p[3 * i1 + 2];
        float cx = p[3 * i2], cy = p[3 * i2 + 1], cz = p[3 * i2 + 2];

        const float third = 1.0f / 3.0f;
        float mx = (ax + bx + cx) * third;
        float my = (ay + by + cy) * third;
        float mz = (az + bz + cz) * third;
        float c2 = mx * mx + my * my + mz * mz;

        float e1x = bx - ax, e1y = by - ay, e1z = bz - az;
        float e2x = cx - ax, e2y = cy - ay, e2z = cz - az;
        float nx = e1y * e2z - e1z * e2y;
        float ny = e1z * e2x - e1x * e2z;
        float nz = e1x * e2y - e1y * e2x;
        float len = sqrtf(nx * nx + ny * ny + nz * nz);
        float inv = 1.0f / fmaxf(len, 1e-12f);

        centers4[i] = make_float4(mx, my, mz, c2);
        normals4[i] = make_float4(nx * inv, ny * inv, nz * inv, 0.0f);

        unsigned bhx = f2bf(mx), bhy = f2bf(my), bhz = f2bf(mz);
        unsigned blx = f2bf(mx - bf2f(bhx)), bly = f2bf(my - bf2f(bhy)), blz = f2bf(mz - bf2f(bhz));
        unsigned c2h = f2bf(c2);
        unsigned c2l = f2bf(c2 - bf2f(c2h));

        int tile = f >> 5, n = f & 31;
        uint4* bb = b_frags + (size_t)(b * FC_TILES + tile) * 64;
        bb[n]      = make_uint4(pk(bhx, bhy), pk(bhz, bhx), pk(bhy, bhz), pk(blx, bly)); // k0..7
        bb[32 + n] = make_uint4(pk(blz, blx), pk(bly, blz), pk(c2h, c2l), pk(ONE, ONE)); // k8..15
    }

    // ---- points ----
    if (i < NB * NP) {
        keys[i] = 0xFFFFFFFFu;
        int pb = i / NP, pn = i & (NP - 1);
        float x = pred[3 * (size_t)i], y = pred[3 * (size_t)i + 1], z = pred[3 * (size_t)i + 2];
        unsigned hx = f2bf(x), hy = f2bf(y), hz = f2bf(z);
        float rx = x - bf2f(hx), ry = y - bf2f(hy), rz = z - bf2f(hz);
        unsigned ahx = f2bf(-2.f * bf2f(hx)), ahy = f2bf(-2.f * bf2f(hy)), ahz = f2bf(-2.f * bf2f(hz));
        unsigned alx = f2bf(-2.f * rx), aly = f2bf(-2.f * ry), alz = f2bf(-2.f * rz);
        float p2 = x * x + y * y + z * z + BIAS;
        unsigned p2h = f2bf(p2);
        unsigned p2l = f2bf(p2 - bf2f(p2h));

        int tile = pn >> 5, m = pn & 31;
        uint4* ab = a_frags + (size_t)(pb * PT_TILES + tile) * 64;
        ab[m]      = make_uint4(pk(ahx, ahy), pk(ahz, alx), pk(aly, alz), pk(ahx, ahy)); // k0..7
        ab[32 + m] = make_uint4(pk(ahz, alx), pk(aly, alz), pk(ONE, ONE), pk(p2h, p2l)); // k8..15
    }
}

// One epilogue triple: k0=(D0&mask)|vf ; k1=(D1&mask)|vf32 ; best=min3
#define EP(D0, D1, BB) \
    "v_and_or_b32 v56, " D0 ", %[m], v58\n\t" \
    "v_and_or_b32 v57, " D1 ", %[m], v60\n\t" \
    "v_min3_u32 " BB ", " BB ", v56, v57\n\t"

// One face-tile pair: 2 LDS reads, 2 MFMAs, 48-instr epilogue. All pinned.
#define PAIR(O0, O1) \
    "ds_read_b128 v[48:51], v59 offset:" O0 "\n\t" \
    "ds_read_b128 v[52:55], v59 offset:" O1 "\n\t" \
    "s_waitcnt lgkmcnt(0)\n\t" \
    "v_mfma_f32_32x32x16_bf16 v[0:15], %[fa], v[48:51], %[fz]\n\t" \
    "v_mfma_f32_32x32x16_bf16 v[16:31], %[fa], v[52:55], %[fz]\n\t" \
    "v_add_u32 v60, 32, v58\n\t" \
    "s_nop 7\n\t" \
    "s_nop 7\n\t" \
    "s_nop 7\n\t" \
    EP("v0",  "v16", "v32") EP("v1",  "v17", "v33") \
    EP("v2",  "v18", "v34") EP("v3",  "v19", "v35") \
    EP("v4",  "v20", "v36") EP("v5",  "v21", "v37") \
    EP("v6",  "v22", "v38") EP("v7",  "v23", "v39") \
    EP("v8",  "v24", "v40") EP("v9",  "v25", "v41") \
    EP("v10", "v26", "v42") EP("v11", "v27", "v43") \
    EP("v12", "v28", "v44") EP("v13", "v29", "v45") \
    EP("v14", "v30", "v46") EP("v15", "v31", "v47") \
    "v_add_u32 v58, 64, v58\n\t"

// ---------------------------------------------------------------------------
// 1-NN on the matrix pipe: the ENTIRE hot loop is one asm volatile block with
// explicitly pinned registers. r12's VGPR_Count=48 proved the compiler parks
// MFMA results/best in AGPRs BETWEEN asm statements and pays accvgpr moves
// per element (~112 VALU instr/iter vs 50 in source). Inside one block with
// clobbered v0-v60 nothing can be inserted. Layout:
//   v[0:15]=d0  v[16:31]=d1  v[32:47]=best  v[48:55]=fb0/fb1
//   v56/v57=k0/k1  v58=vf  v59=lds addr  v60=vf+32
// best is init'd (-1) and extracted inside the same block. One 32KB LDS
// stage (32 tiles, 16-bit ds offsets 0..31744), one __syncthreads.
// C/D layout verified r4-r12 (absmax 0.0):
//   col(face)=lane&31, row(point)=(reg&3)+8*(reg>>2)+4*(lane>>5).
// key = (bits(dist^2+BIAS) & 0xFFFFC000) | face_idx; cross-slice atomicMin.
// ---------------------------------------------------------------------------
__global__ __launch_bounds__(TPB) void nn_kernel(
        const uint4* __restrict__ a_frags,
        const uint4* __restrict__ b_frags,
        unsigned* __restrict__ keys) {
    const int pg = blockIdx.x, sl = blockIdx.y, b = blockIdx.z;
    const int tid = threadIdx.x, wave = tid >> 6, lane = tid & 63;

    __shared__ uint4 sb[SL_TILES * 64];        // 32 KB

    // one 32-point A-tile per wave
    const int pt_tile = pg * 4 + wave;
    FragU a;
    a.u = a_frags[((size_t)(b * PT_TILES + pt_tile)) * 64 + lane];

    // stage the whole 32-tile slice once
    const uint4* gsrc = b_frags + ((size_t)(b * FC_TILES + sl * SL_TILES)) * 64;
#pragma unroll
    for (int k = 0; k < (SL_TILES * 64) / TPB; ++k)
        sb[k * TPB + tid] = gsrc[k * TPB + tid];
    __syncthreads();

    const floatx16 zero = {0.f, 0.f, 0.f, 0.f, 0.f, 0.f, 0.f, 0.f,
                           0.f, 0.f, 0.f, 0.f, 0.f, 0.f, 0.f, 0.f};
    const unsigned mask = 0xFFFFC000u;
    const unsigned vf_base = (unsigned)(sl * (SL_TILES * 32) + (lane & 31));
    // shared aperture is 2^48-aligned -> low 32 bits of the flat address are
    // the LDS segment offset.
    const unsigned lds_base = (unsigned)(unsigned long long)&sb[lane];

    unsigned b0, b1, b2, b3, b4, b5, b6, b7, b8, b9, b10, b11, b12, b13, b14, b15;
    asm volatile(
        "v_mov_b32 v59, %[lb]\n\t"
        "v_mov_b32 v58, %[vfb]\n\t"
        "v_mov_b32 v32, -1\n\t" "v_mov_b32 v33, -1\n\t"
        "v_mov_b32 v34, -1\n\t" "v_mov_b32 v35, -1\n\t"
        "v_mov_b32 v36, -1\n\t" "v_mov_b32 v37, -1\n\t"
        "v_mov_b32 v38, -1\n\t" "v_mov_b32 v39, -1\n\t"
        "v_mov_b32 v40, -1\n\t" "v_mov_b32 v41, -1\n\t"
        "v_mov_b32 v42, -1\n\t" "v_mov_b32 v43, -1\n\t"
        "v_mov_b32 v44, -1\n\t" "v_mov_b32 v45, -1\n\t"
        "v_mov_b32 v46, -1\n\t" "v_mov_b32 v47, -1\n\t"
        PAIR("0",     "1024")
        PAIR("2048",  "3072")
        PAIR("4096",  "5120")
        PAIR("6144",  "7168")
        PAIR("8192",  "9216")
        PAIR("10240", "11264")
        PAIR("12288", "13312")
        PAIR("14336", "15360")
        PAIR("16384", "17408")
        PAIR("18432", "19456")
        PAIR("20480", "21504")
        PAIR("22528", "23552")
        PAIR("24576", "25600")
        PAIR("26624", "27648")
        PAIR("28672", "29696")
        PAIR("30720", "31744")
        "v_mov_b32 %0, v32\n\t"  "v_mov_b32 %1, v33\n\t"
        "v_mov_b32 %2, v34\n\t"  "v_mov_b32 %3, v35\n\t"
        "v_mov_b32 %4, v36\n\t"  "v_mov_b32 %5, v37\n\t"
        "v_mov_b32 %6, v38\n\t"  "v_mov_b32 %7, v39\n\t"
        "v_mov_b32 %8, v40\n\t"  "v_mov_b32 %9, v41\n\t"
        "v_mov_b32 %10, v42\n\t" "v_mov_b32 %11, v43\n\t"
        "v_mov_b32 %12, v44\n\t" "v_mov_b32 %13, v45\n\t"
        "v_mov_b32 %14, v46\n\t" "v_mov_b32 %15, v47"
        : "=v"(b0), "=v"(b1), "=v"(b2), "=v"(b3),
          "=v"(b4), "=v"(b5), "=v"(b6), "=v"(b7),
          "=v"(b8), "=v"(b9), "=v"(b10), "=v"(b11),
          "=v"(b12), "=v"(b13), "=v"(b14), "=v"(b15)
        : [fa]"v"(a.s), [fz]"v"(zero), [m]"s"(mask),
          [vfb]"v"(vf_base), [lb]"v"(lds_base)
        : "v0","v1","v2","v3","v4","v5","v6","v7",
          "v8","v9","v10","v11","v12","v13","v14","v15",
          "v16","v17","v18","v19","v20","v21","v22","v23",
          "v24","v25","v26","v27","v28","v29","v30","v31",
          "v32","v33","v34","v35","v36","v37","v38","v39",
          "v40","v41","v42","v43","v44","v45","v46","v47",
          "v48","v49","v50","v51","v52","v53","v54","v55",
          "v56","v57","v58","v59","v60","memory");

    unsigned best[16] = {b0, b1, b2, b3, b4, b5, b6, b7,
                         b8, b9, b10, b11, b12, b13, b14, b15};

    // min across the 32 face-columns (stays within each 32-lane half)
#pragma unroll
    for (int e = 0; e < 16; ++e) {
        unsigned v = best[e];
#pragma unroll
        for (int m = 1; m < 32; m <<= 1)
            v = min(v, (unsigned)__shfl_xor((int)v, m, 64));
        best[e] = v;
    }
    unsigned* kb = keys + b * NP;
    if ((lane & 31) == 0) {
        int half = lane >> 5;
#pragma unroll
        for (int r = 0; r < 16; ++r) {
            int row = (r & 3) + 8 * (r >> 2) + 4 * half;
            atomicMin(&kb[pt_tile * 32 + row], best[r]);
        }
    }
}

// ---------------------------------------------------------------------------
// Per-point signed plane distance -> interp^3 sum + hit count; the LAST of
// the 128 blocks (device ticket) writes d_out. Fence cost is trivial here.
// ---------------------------------------------------------------------------
__global__ __launch_bounds__(TPB) void finalize_kernel(
        const float* __restrict__ pred,
        const float4* __restrict__ centers4,
        const float4* __restrict__ normals4,
        const unsigned int* __restrict__ keys,
        float* __restrict__ acc,
        unsigned* __restrict__ tk,
        float* __restrict__ out,
        int nblocks) {
    int i = blockIdx.x * blockDim.x + threadIdx.x;   // 0 .. B*N-1
    float val = 0.0f, cnt = 0.0f;
    if (i < NB * NP) {
        int b = i / NP;
        unsigned key = keys[i];
        int idx = (int)(key & (unsigned)(NF - 1));
        float4 c  = centers4[b * NF + idx];
        float4 nr = normals4[b * NF + idx];
        const float* pp = pred + (size_t)i * 3;
        float dx = pp[0] - c.x, dy = pp[1] - c.y, dz = pp[2] - c.z;
        float dist = dx * nr.x + dy * nr.y + dz * nr.z;
        float t = F_EPS - dist;
        if (t > 0.0f) { cnt = 1.0f; val = t * t * t; }
    }
    for (int off = 32; off > 0; off >>= 1) {
        val += __shfl_down(val, off, 64);
        cnt += __shfl_down(cnt, off, 64);
    }
    __shared__ float sv[TPB / 64], sn[TPB / 64];
    __shared__ unsigned s_tkt;
    int lane = threadIdx.x & 63, wave = threadIdx.x >> 6;
    if (lane == 0) { sv[wave] = val; sn[wave] = cnt; }
    __syncthreads();
    if (threadIdx.x == 0) {
        float v = 0.0f, cc = 0.0f;
#pragma unroll
        for (int w = 0; w < TPB / 64; ++w) { v += sv[w]; cc += sn[w]; }
        atomicAdd(&acc[0], v);
        atomicAdd(&acc[1], cc);
        __threadfence();
        s_tkt = atomicAdd(&tk[0], 1u);
        if (s_tkt == (unsigned)(nblocks - 1)) {      // last block writes out
            float a0 = __hip_atomic_load(&acc[0], __ATOMIC_RELAXED, __HIP_MEMORY_SCOPE_AGENT);
            float a1 = __hip_atomic_load(&acc[1], __ATOMIC_RELAXED, __HIP_MEMORY_SCOPE_AGENT);
            out[0] = a0 * (F_WEIGHT / (float)NB);
            out[1] = a1 * (1.0f / (float)(NB * NP));
        }
    }
}

extern "C" void kernel_launch(void* const* d_in, const int* in_sizes, int n_in,
                              void* d_out, int out_size, void* d_ws, size_t ws_size,
                              hipStream_t stream) {
    const float* pred  = (const float*)d_in[0];   // [B,N,3] f32
    const float* opos  = (const float*)d_in[1];   // [B,V,3] f32
    const int*   faces = (const int*)  d_in[2];   // [B,F,3] i32

    char* ws = (char*)d_ws;
    const size_t a_bytes = (size_t)NB * PT_TILES * 64 * 16;   // 1 MiB
    const size_t b_bytes = (size_t)NB * FC_TILES * 64 * 16;   // 2 MiB
    const size_t c_bytes = (size_t)NB * NF * 16;              // 1 MiB
    const size_t k_bytes = (size_t)NB * NP * sizeof(unsigned);// 128 KiB

    uint4*    a_frags  = (uint4*)ws;
    uint4*    b_frags  = (uint4*)(ws + a_bytes);
    float4*   centers4 = (float4*)(ws + a_bytes + b_bytes);
    float4*   normals4 = (float4*)(ws + a_bytes + b_bytes + c_bytes);
    unsigned* keys     = (unsigned*)(ws + a_bytes + b_bytes + 2 * c_bytes);
    float*    acc      = (float*)(ws + a_bytes + b_bytes + 2 * c_bytes + k_bytes);
    unsigned* tk       = (unsigned*)(ws + a_bytes + b_bytes + 2 * c_bytes + k_bytes + 64);

    prep_kernel<<<(NB * NF + TPB - 1) / TPB, TPB, 0, stream>>>(
        pred, opos, faces, a_frags, b_frags, centers4, normals4, keys, acc, tk);

    nn_kernel<<<dim3(PGB, FS, NB), TPB, 0, stream>>>(a_frags, b_frags, keys);

    int fin_blocks = (NB * NP + TPB - 1) / TPB;
    finalize_kernel<<<fin_blocks, TPB, 0, stream>>>(
        pred, centers4, normals4, keys, acc, tk, (float*)d_out, fin_blocks);
}

// Round 14
// 104.870 us; speedup vs baseline: 1.0799x; 1.0056x over previous
//
#include <hip/hip_runtime.h>
#include <cstdint>

typedef __attribute__((ext_vector_type(8)))  short short8;
typedef __attribute__((ext_vector_type(16))) float floatx16;

constexpr int NB = 4;        // batch
constexpr int NV = 8192;     // vertices
constexpr int NF = 16384;    // faces
constexpr int NP = 8192;     // query points per batch
constexpr float F_EPS = 1e-3f;
constexpr float F_WEIGHT = 1000.0f;
constexpr float BIAS = 1e-3f;        // keeps dist^2 > 0 despite bf16 rounding

constexpr int PT_TILES = NP / 32;        // 256 point tiles (32-wide) / batch
constexpr int FC_TILES = NF / 32;        // 512 face tiles (32-wide) / batch
constexpr int TPB = 256;                 // 4 waves
constexpr int FS = 16;                   // face slices
constexpr int SL_TILES = FC_TILES / FS;  // 32 face tiles (1024 faces) / slice -> 32KB LDS
constexpr int PGB = 64;                  // point groups (128 pts) / batch
// grid = PGB x FS x NB = 4096 blocks

union FragU { uint4 u; short8 s; };

__device__ inline unsigned f2bf(float f) {           // fp32 -> bf16 (RNE)
    unsigned u = __float_as_uint(f);
    return (u + 0x7FFFu + ((u >> 16) & 1u)) >> 16;
}
__device__ inline float bf2f(unsigned h) { return __uint_as_float(h << 16); }
__device__ inline unsigned pk(unsigned lo, unsigned hi) {
    return (lo & 0xFFFFu) | (hi << 16);
}

// ---------------------------------------------------------------------------
// Fused prep (unchanged; verified absmax 0.0 through r6-r13).
// ---------------------------------------------------------------------------
__global__ void prep_kernel(const float* __restrict__ pred,
                            const float* __restrict__ pos,
                            const int*   __restrict__ faces,
                            uint4* __restrict__ a_frags,
                            uint4* __restrict__ b_frags,
                            float4* __restrict__ centers4,
                            float4* __restrict__ normals4,
                            unsigned* __restrict__ keys,
                            float* __restrict__ acc,
                            unsigned* __restrict__ tk) {
    int i = blockIdx.x * blockDim.x + threadIdx.x;   // [0, NB*NF)
    if (i >= NB * NF) return;
    if (i < 2) acc[i] = 0.0f;
    if (i == 0) tk[0] = 0u;

    const unsigned ONE = 0x3F80u;

    // ---- faces ----
    {
        int b = i / NF, f = i & (NF - 1);
        const float* p = pos + (size_t)b * NV * 3;
        int i0 = faces[3 * (size_t)i], i1 = faces[3 * (size_t)i + 1], i2 = faces[3 * (size_t)i + 2];
        float ax = p[3 * i0], ay = p[3 * i0 + 1], az = p[3 * i0 + 2];
        float bx = p[3 * i1], by = p[3 * i1 + 1], bz = p[3 * i1 + 2];
        float cx = p[3 * i2], cy = p[3 * i2 + 1], cz = p[3 * i2 + 2];

        const float third = 1.0f / 3.0f;
        float mx = (ax + bx + cx) * third;
        float my = (ay + by + cy) * third;
        float mz = (az + bz + cz) * third;
        float c2 = mx * mx + my * my + mz * mz;

        float e1x = bx - ax, e1y = by - ay, e1z = bz - az;
        float e2x = cx - ax, e2y = cy - ay, e2z = cz - az;
        float nx = e1y * e2z - e1z * e2y;
        float ny = e1z * e2x - e1x * e2z;
        float nz = e1x * e2y - e1y * e2x;
        float len = sqrtf(nx * nx + ny * ny + nz * nz);
        float inv = 1.0f / fmaxf(len, 1e-12f);

        centers4[i] = make_float4(mx, my, mz, c2);
        normals4[i] = make_float4(nx * inv, ny * inv, nz * inv, 0.0f);

        unsigned bhx = f2bf(mx), bhy = f2bf(my), bhz = f2bf(mz);
        unsigned blx = f2bf(mx - bf2f(bhx)), bly = f2bf(my - bf2f(bhy)), blz = f2bf(mz - bf2f(bhz));
        unsigned c2h = f2bf(c2);
        unsigned c2l = f2bf(c2 - bf2f(c2h));

        int tile = f >> 5, n = f & 31;
        uint4* bb = b_frags + (size_t)(b * FC_TILES + tile) * 64;
        bb[n]      = make_uint4(pk(bhx, bhy), pk(bhz, bhx), pk(bhy, bhz), pk(blx, bly)); // k0..7
        bb[32 + n] = make_uint4(pk(blz, blx), pk(bly, blz), pk(c2h, c2l), pk(ONE, ONE)); // k8..15
    }

    // ---- points ----
    if (i < NB * NP) {
        keys[i] = 0xFFFFFFFFu;
        int pb = i / NP, pn = i & (NP - 1);
        float x = pred[3 * (size_t)i], y = pred[3 * (size_t)i + 1], z = pred[3 * (size_t)i + 2];
        unsigned hx = f2bf(x), hy = f2bf(y), hz = f2bf(z);
        float rx = x - bf2f(hx), ry = y - bf2f(hy), rz = z - bf2f(hz);
        unsigned ahx = f2bf(-2.f * bf2f(hx)), ahy = f2bf(-2.f * bf2f(hy)), ahz = f2bf(-2.f * bf2f(hz));
        unsigned alx = f2bf(-2.f * rx), aly = f2bf(-2.f * ry), alz = f2bf(-2.f * rz);
        float p2 = x * x + y * y + z * z + BIAS;
        unsigned p2h = f2bf(p2);
        unsigned p2l = f2bf(p2 - bf2f(p2h));

        int tile = pn >> 5, m = pn & 31;
        uint4* ab = a_frags + (size_t)(pb * PT_TILES + tile) * 64;
        ab[m]      = make_uint4(pk(ahx, ahy), pk(ahz, alx), pk(aly, alz), pk(ahx, ahy)); // k0..7
        ab[32 + m] = make_uint4(pk(ahz, alx), pk(aly, alz), pk(ONE, ONE), pk(p2h, p2l)); // k8..15
    }
}

// One epilogue triple: k0=(D0&mask)|vf ; k1=(D1&mask)|vf32 ; best=min3
#define EP(D0, D1, BB) \
    "v_and_or_b32 v64, " D0 ", %[m], v66\n\t" \
    "v_and_or_b32 v65, " D1 ", %[m], v67\n\t" \
    "v_min3_u32 " BB ", " BB ", v64, v65\n\t"

#define EPILOGUE \
    "v_add_u32 v67, 32, v66\n\t" \
    "s_nop 7\n\t" \
    "s_nop 7\n\t" \
    "s_nop 7\n\t" \
    EP("v0",  "v16", "v32") EP("v1",  "v17", "v33") \
    EP("v2",  "v18", "v34") EP("v3",  "v19", "v35") \
    EP("v4",  "v20", "v36") EP("v5",  "v21", "v37") \
    EP("v6",  "v22", "v38") EP("v7",  "v23", "v39") \
    EP("v8",  "v24", "v40") EP("v9",  "v25", "v41") \
    EP("v10", "v26", "v42") EP("v11", "v27", "v43") \
    EP("v12", "v28", "v44") EP("v13", "v29", "v45") \
    EP("v14", "v30", "v46") EP("v15", "v31", "v47") \
    "v_add_u32 v66, 64, v66\n\t"

// Pair with current operands in fbA (v48-55), prefetch next pair into fbB.
#define PAIR_A(P0, P1) \
    "ds_read_b128 v[56:59], v68 offset:" P0 "\n\t" \
    "ds_read_b128 v[60:63], v68 offset:" P1 "\n\t" \
    "s_waitcnt lgkmcnt(2)\n\t" \
    "v_mfma_f32_32x32x16_bf16 v[0:15], %[fa], v[48:51], %[fz]\n\t" \
    "v_mfma_f32_32x32x16_bf16 v[16:31], %[fa], v[52:55], %[fz]\n\t" \
    EPILOGUE

// Pair with current operands in fbB (v56-63), prefetch next pair into fbA.
#define PAIR_B(P0, P1) \
    "ds_read_b128 v[48:51], v68 offset:" P0 "\n\t" \
    "ds_read_b128 v[52:55], v68 offset:" P1 "\n\t" \
    "s_waitcnt lgkmcnt(2)\n\t" \
    "v_mfma_f32_32x32x16_bf16 v[0:15], %[fa], v[56:59], %[fz]\n\t" \
    "v_mfma_f32_32x32x16_bf16 v[16:31], %[fa], v[60:63], %[fz]\n\t" \
    EPILOGUE

// Last pair (current in fbB), nothing left to prefetch.
#define PAIR_B_LAST \
    "s_waitcnt lgkmcnt(0)\n\t" \
    "v_mfma_f32_32x32x16_bf16 v[0:15], %[fa], v[56:59], %[fz]\n\t" \
    "v_mfma_f32_32x32x16_bf16 v[16:31], %[fa], v[60:63], %[fz]\n\t" \
    EPILOGUE

// ---------------------------------------------------------------------------
// 1-NN on the matrix pipe: r13's single asm mega-block + software-pipelined
// LDS reads. r13's counters showed block-serial execution (43.5us vs ~10.7us
// VALU / 10.2us LDS pipe floors): every iteration ate the full LDS
// load-to-use latency behind s_waitcnt lgkmcnt(0) with only ~2.6 resident
// waves/SIMD to cover it. Now each pair prefetches the NEXT pair's B-tiles
// into the alternate register buffer (fbA=v[48:55] <-> fbB=v[56:63]) and
// waits lgkmcnt(2) (= current pair ready), hiding the LDS latency behind the
// ~150-cyc epilogue. Layout: v[0:15]=d0 v[16:31]=d1 v[32:47]=best
// v48-63=fbA/fbB v64/v65=k0/k1 v66=vf v67=vf+32 v68=lds addr.
// C/D layout verified r4-r13 (absmax 0.0):
//   col(face)=lane&31, row(point)=(reg&3)+8*(reg>>2)+4*(lane>>5).
// key = (bits(dist^2+BIAS) & 0xFFFFC000) | face_idx; cross-slice atomicMin.
// ---------------------------------------------------------------------------
__global__ __launch_bounds__(TPB) void nn_kernel(
        const uint4* __restrict__ a_frags,
        const uint4* __restrict__ b_frags,
        unsigned* __restrict__ keys) {
    const int pg = blockIdx.x, sl = blockIdx.y, b = blockIdx.z;
    const int tid = threadIdx.x, wave = tid >> 6, lane = tid & 63;

    __shared__ uint4 sb[SL_TILES * 64];        // 32 KB

    // one 32-point A-tile per wave
    const int pt_tile = pg * 4 + wave;
    FragU a;
    a.u = a_frags[((size_t)(b * PT_TILES + pt_tile)) * 64 + lane];

    // stage the whole 32-tile slice once
    const uint4* gsrc = b_frags + ((size_t)(b * FC_TILES + sl * SL_TILES)) * 64;
#pragma unroll
    for (int k = 0; k < (SL_TILES * 64) / TPB; ++k)
        sb[k * TPB + tid] = gsrc[k * TPB + tid];
    __syncthreads();

    const floatx16 zero = {0.f, 0.f, 0.f, 0.f, 0.f, 0.f, 0.f, 0.f,
                           0.f, 0.f, 0.f, 0.f, 0.f, 0.f, 0.f, 0.f};
    const unsigned mask = 0xFFFFC000u;
    const unsigned vf_base = (unsigned)(sl * (SL_TILES * 32) + (lane & 31));
    // shared aperture is 2^48-aligned -> low 32 bits of the flat address are
    // the LDS segment offset.
    const unsigned lds_base = (unsigned)(unsigned long long)&sb[lane];

    unsigned b0, b1, b2, b3, b4, b5, b6, b7, b8, b9, b10, b11, b12, b13, b14, b15;
    asm volatile(
        "v_mov_b32 v68, %[lb]\n\t"
        "v_mov_b32 v66, %[vfb]\n\t"
        "v_mov_b32 v32, -1\n\t" "v_mov_b32 v33, -1\n\t"
        "v_mov_b32 v34, -1\n\t" "v_mov_b32 v35, -1\n\t"
        "v_mov_b32 v36, -1\n\t" "v_mov_b32 v37, -1\n\t"
        "v_mov_b32 v38, -1\n\t" "v_mov_b32 v39, -1\n\t"
        "v_mov_b32 v40, -1\n\t" "v_mov_b32 v41, -1\n\t"
        "v_mov_b32 v42, -1\n\t" "v_mov_b32 v43, -1\n\t"
        "v_mov_b32 v44, -1\n\t" "v_mov_b32 v45, -1\n\t"
        "v_mov_b32 v46, -1\n\t" "v_mov_b32 v47, -1\n\t"
        // preload pair 0 into fbA
        "ds_read_b128 v[48:51], v68 offset:0\n\t"
        "ds_read_b128 v[52:55], v68 offset:1024\n\t"
        PAIR_A("2048",  "3072")     // pair 0  (prefetch pair 1)
        PAIR_B("4096",  "5120")     // pair 1  (prefetch pair 2)
        PAIR_A("6144",  "7168")
        PAIR_B("8192",  "9216")
        PAIR_A("10240", "11264")
        PAIR_B("12288", "13312")
        PAIR_A("14336", "15360")
        PAIR_B("16384", "17408")
        PAIR_A("18432", "19456")
        PAIR_B("20480", "21504")
        PAIR_A("22528", "23552")
        PAIR_B("24576", "25600")
        PAIR_A("26624", "27648")
        PAIR_B("28672", "29696")
        PAIR_A("30720", "31744")    // pair 14 (prefetch pair 15)
        PAIR_B_LAST                 // pair 15
        "v_mov_b32 %0, v32\n\t"  "v_mov_b32 %1, v33\n\t"
        "v_mov_b32 %2, v34\n\t"  "v_mov_b32 %3, v35\n\t"
        "v_mov_b32 %4, v36\n\t"  "v_mov_b32 %5, v37\n\t"
        "v_mov_b32 %6, v38\n\t"  "v_mov_b32 %7, v39\n\t"
        "v_mov_b32 %8, v40\n\t"  "v_mov_b32 %9, v41\n\t"
        "v_mov_b32 %10, v42\n\t" "v_mov_b32 %11, v43\n\t"
        "v_mov_b32 %12, v44\n\t" "v_mov_b32 %13, v45\n\t"
        "v_mov_b32 %14, v46\n\t" "v_mov_b32 %15, v47"
        : "=v"(b0), "=v"(b1), "=v"(b2), "=v"(b3),
          "=v"(b4), "=v"(b5), "=v"(b6), "=v"(b7),
          "=v"(b8), "=v"(b9), "=v"(b10), "=v"(b11),
          "=v"(b12), "=v"(b13), "=v"(b14), "=v"(b15)
        : [fa]"v"(a.s), [fz]"v"(zero), [m]"s"(mask),
          [vfb]"v"(vf_base), [lb]"v"(lds_base)
        : "v0","v1","v2","v3","v4","v5","v6","v7",
          "v8","v9","v10","v11","v12","v13","v14","v15",
          "v16","v17","v18","v19","v20","v21","v22","v23",
          "v24","v25","v26","v27","v28","v29","v30","v31",
          "v32","v33","v34","v35","v36","v37","v38","v39",
          "v40","v41","v42","v43","v44","v45","v46","v47",
          "v48","v49","v50","v51","v52","v53","v54","v55",
          "v56","v57","v58","v59","v60","v61","v62","v63",
          "v64","v65","v66","v67","v68","memory");

    unsigned best[16] = {b0, b1, b2, b3, b4, b5, b6, b7,
                         b8, b9, b10, b11, b12, b13, b14, b15};

    // min across the 32 face-columns (stays within each 32-lane half)
#pragma unroll
    for (int e = 0; e < 16; ++e) {
        unsigned v = best[e];
#pragma unroll
        for (int m = 1; m < 32; m <<= 1)
            v = min(v, (unsigned)__shfl_xor((int)v, m, 64));
        best[e] = v;
    }
    unsigned* kb = keys + b * NP;
    if ((lane & 31) == 0) {
        int half = lane >> 5;
#pragma unroll
        for (int r = 0; r < 16; ++r) {
            int row = (r & 3) + 8 * (r >> 2) + 4 * half;
            atomicMin(&kb[pt_tile * 32 + row], best[r]);
        }
    }
}

// ---------------------------------------------------------------------------
// Per-point signed plane distance -> interp^3 sum + hit count; the LAST of
// the 128 blocks (device ticket) writes d_out. Fence cost is trivial here.
// ---------------------------------------------------------------------------
__global__ __launch_bounds__(TPB) void finalize_kernel(
        const float* __restrict__ pred,
        const float4* __restrict__ centers4,
        const float4* __restrict__ normals4,
        const unsigned int* __restrict__ keys,
        float* __restrict__ acc,
        unsigned* __restrict__ tk,
        float* __restrict__ out,
        int nblocks) {
    int i = blockIdx.x * blockDim.x + threadIdx.x;   // 0 .. B*N-1
    float val = 0.0f, cnt = 0.0f;
    if (i < NB * NP) {
        int b = i / NP;
        unsigned key = keys[i];
        int idx = (int)(key & (unsigned)(NF - 1));
        float4 c  = centers4[b * NF + idx];
        float4 nr = normals4[b * NF + idx];
        const float* pp = pred + (size_t)i * 3;
        float dx = pp[0] - c.x, dy = pp[1] - c.y, dz = pp[2] - c.z;
        float dist = dx * nr.x + dy * nr.y + dz * nr.z;
        float t = F_EPS - dist;
        if (t > 0.0f) { cnt = 1.0f; val = t * t * t; }
    }
    for (int off = 32; off > 0; off >>= 1) {
        val += __shfl_down(val, off, 64);
        cnt += __shfl_down(cnt, off, 64);
    }
    __shared__ float sv[TPB / 64], sn[TPB / 64];
    __shared__ unsigned s_tkt;
    int lane = threadIdx.x & 63, wave = threadIdx.x >> 6;
    if (lane == 0) { sv[wave] = val; sn[wave] = cnt; }
    __syncthreads();
    if (threadIdx.x == 0) {
        float v = 0.0f, cc = 0.0f;
#pragma unroll
        for (int w = 0; w < TPB / 64; ++w) { v += sv[w]; cc += sn[w]; }
        atomicAdd(&acc[0], v);
        atomicAdd(&acc[1], cc);
        __threadfence();
        s_tkt = atomicAdd(&tk[0], 1u);
        if (s_tkt == (unsigned)(nblocks - 1)) {      // last block writes out
            float a0 = __hip_atomic_load(&acc[0], __ATOMIC_RELAXED, __HIP_MEMORY_SCOPE_AGENT);
            float a1 = __hip_atomic_load(&acc[1], __ATOMIC_RELAXED, __HIP_MEMORY_SCOPE_AGENT);
            out[0] = a0 * (F_WEIGHT / (float)NB);
            out[1] = a1 * (1.0f / (float)(NB * NP));
        }
    }
}

extern "C" void kernel_launch(void* const* d_in, const int* in_sizes, int n_in,
                              void* d_out, int out_size, void* d_ws, size_t ws_size,
                              hipStream_t stream) {
    const float* pred  = (const float*)d_in[0];   // [B,N,3] f32
    const float* opos  = (const float*)d_in[1];   // [B,V,3] f32
    const int*   faces = (const int*)  d_in[2];   // [B,F,3] i32

    char* ws = (char*)d_ws;
    const size_t a_bytes = (size_t)NB * PT_TILES * 64 * 16;   // 1 MiB
    const size_t b_bytes = (size_t)NB * FC_TILES * 64 * 16;   // 2 MiB
    const size_t c_bytes = (size_t)NB * NF * 16;              // 1 MiB
    const size_t k_bytes = (size_t)NB * NP * sizeof(unsigned);// 128 KiB

    uint4*    a_frags  = (uint4*)ws;
    uint4*    b_frags  = (uint4*)(ws + a_bytes);
    float4*   centers4 = (float4*)(ws + a_bytes + b_bytes);
    float4*   normals4 = (float4*)(ws + a_bytes + b_bytes + c_bytes);
    unsigned* keys     = (unsigned*)(ws + a_bytes + b_bytes + 2 * c_bytes);
    float*    acc      = (float*)(ws + a_bytes + b_bytes + 2 * c_bytes + k_bytes);
    unsigned* tk       = (unsigned*)(ws + a_bytes + b_bytes + 2 * c_bytes + k_bytes + 64);

    prep_kernel<<<(NB * NF + TPB - 1) / TPB, TPB, 0, stream>>>(
        pred, opos, faces, a_frags, b_frags, centers4, normals4, keys, acc, tk);

    nn_kernel<<<dim3(PGB, FS, NB), TPB, 0, stream>>>(a_frags, b_frags, keys);

    int fin_blocks = (NB * NP + TPB - 1) / TPB;
    finalize_kernel<<<fin_blocks, TPB, 0, stream>>>(
        pred, centers4, normals4, keys, acc, tk, (float*)d_out, fin_blocks);
}

// Round 15
// 104.636 us; speedup vs baseline: 1.0823x; 1.0022x over previous
//
#include <hip/hip_runtime.h>
#include <cstdint>

typedef __attribute__((ext_vector_type(8)))  short short8;
typedef __attribute__((ext_vector_type(16))) float floatx16;

constexpr int NB = 4;        // batch
constexpr int NV = 8192;     // vertices
constexpr int NF = 16384;    // faces
constexpr int NP = 8192;     // query points per batch
constexpr float F_EPS = 1e-3f;
constexpr float F_WEIGHT = 1000.0f;
constexpr float BIAS = 1e-3f;        // keeps dist^2 > 0 despite bf16 rounding

constexpr int PT_TILES = NP / 32;        // 256 point tiles (32-wide) / batch
constexpr int FC_TILES = NF / 32;        // 512 face tiles (32-wide) / batch
constexpr int TPB = 256;                 // 4 waves
constexpr int FS = 16;                   // face slices
constexpr int SL_TILES = FC_TILES / FS;  // 32 face tiles (1024 faces) / slice -> 32KB LDS
constexpr int PGB = 64;                  // point groups (128 pts) / batch
// grid = PGB x FS x NB = 4096 blocks

union FragU { uint4 u; short8 s; };

__device__ inline unsigned f2bf(float f) {           // fp32 -> bf16 (RNE)
    unsigned u = __float_as_uint(f);
    return (u + 0x7FFFu + ((u >> 16) & 1u)) >> 16;
}
__device__ inline float bf2f(unsigned h) { return __uint_as_float(h << 16); }
__device__ inline unsigned pk(unsigned lo, unsigned hi) {
    return (lo & 0xFFFFu) | (hi << 16);
}

// ---------------------------------------------------------------------------
// Fused prep (unchanged; verified absmax 0.0 through r6-r14).
// ---------------------------------------------------------------------------
__global__ void prep_kernel(const float* __restrict__ pred,
                            const float* __restrict__ pos,
                            const int*   __restrict__ faces,
                            uint4* __restrict__ a_frags,
                            uint4* __restrict__ b_frags,
                            float4* __restrict__ centers4,
                            float4* __restrict__ normals4,
                            unsigned* __restrict__ keys,
                            float* __restrict__ acc,
                            unsigned* __restrict__ tk) {
    int i = blockIdx.x * blockDim.x + threadIdx.x;   // [0, NB*NF)
    if (i >= NB * NF) return;
    if (i < 2) acc[i] = 0.0f;
    if (i == 0) tk[0] = 0u;

    const unsigned ONE = 0x3F80u;

    // ---- faces ----
    {
        int b = i / NF, f = i & (NF - 1);
        const float* p = pos + (size_t)b * NV * 3;
        int i0 = faces[3 * (size_t)i], i1 = faces[3 * (size_t)i + 1], i2 = faces[3 * (size_t)i + 2];
        float ax = p[3 * i0], ay = p[3 * i0 + 1], az = p[3 * i0 + 2];
        float bx = p[3 * i1], by = p[3 * i1 + 1], bz = p[3 * i1 + 2];
        float cx = p[3 * i2], cy = p[3 * i2 + 1], cz = p[3 * i2 + 2];

        const float third = 1.0f / 3.0f;
        float mx = (ax + bx + cx) * third;
        float my = (ay + by + cy) * third;
        float mz = (az + bz + cz) * third;
        float c2 = mx * mx + my * my + mz * mz;

        float e1x = bx - ax, e1y = by - ay, e1z = bz - az;
        float e2x = cx - ax, e2y = cy - ay, e2z = cz - az;
        float nx = e1y * e2z - e1z * e2y;
        float ny = e1z * e2x - e1x * e2z;
        float nz = e1x * e2y - e1y * e2x;
        float len = sqrtf(nx * nx + ny * ny + nz * nz);
        float inv = 1.0f / fmaxf(len, 1e-12f);

        centers4[i] = make_float4(mx, my, mz, c2);
        normals4[i] = make_float4(nx * inv, ny * inv, nz * inv, 0.0f);

        unsigned bhx = f2bf(mx), bhy = f2bf(my), bhz = f2bf(mz);
        unsigned blx = f2bf(mx - bf2f(bhx)), bly = f2bf(my - bf2f(bhy)), blz = f2bf(mz - bf2f(bhz));
        unsigned c2h = f2bf(c2);
        unsigned c2l = f2bf(c2 - bf2f(c2h));

        int tile = f >> 5, n = f & 31;
        uint4* bb = b_frags + (size_t)(b * FC_TILES + tile) * 64;
        bb[n]      = make_uint4(pk(bhx, bhy), pk(bhz, bhx), pk(bhy, bhz), pk(blx, bly)); // k0..7
        bb[32 + n] = make_uint4(pk(blz, blx), pk(bly, blz), pk(c2h, c2l), pk(ONE, ONE)); // k8..15
    }

    // ---- points ----
    if (i < NB * NP) {
        keys[i] = 0xFFFFFFFFu;
        int pb = i / NP, pn = i & (NP - 1);
        float x = pred[3 * (size_t)i], y = pred[3 * (size_t)i + 1], z = pred[3 * (size_t)i + 2];
        unsigned hx = f2bf(x), hy = f2bf(y), hz = f2bf(z);
        float rx = x - bf2f(hx), ry = y - bf2f(hy), rz = z - bf2f(hz);
        unsigned ahx = f2bf(-2.f * bf2f(hx)), ahy = f2bf(-2.f * bf2f(hy)), ahz = f2bf(-2.f * bf2f(hz));
        unsigned alx = f2bf(-2.f * rx), aly = f2bf(-2.f * ry), alz = f2bf(-2.f * rz);
        float p2 = x * x + y * y + z * z + BIAS;
        unsigned p2h = f2bf(p2);
        unsigned p2l = f2bf(p2 - bf2f(p2h));

        int tile = pn >> 5, m = pn & 31;
        uint4* ab = a_frags + (size_t)(pb * PT_TILES + tile) * 64;
        ab[m]      = make_uint4(pk(ahx, ahy), pk(ahz, alx), pk(aly, alz), pk(ahx, ahy)); // k0..7
        ab[32 + m] = make_uint4(pk(ahz, alx), pk(aly, alz), pk(ONE, ONE), pk(p2h, p2l)); // k8..15
    }
}

// One epilogue triple: k0=(D0&mask)|vf ; k1=(D1&mask)|vf32 ; best=min3
#define EP(D0, D1, BB) \
    "v_and_or_b32 v64, " D0 ", %[m], v66\n\t" \
    "v_and_or_b32 v65, " D1 ", %[m], v67\n\t" \
    "v_min3_u32 " BB ", " BB ", v64, v65\n\t"

#define EPILOGUE \
    "v_add_u32 v67, 32, v66\n\t" \
    "s_nop 7\n\t" \
    "s_nop 7\n\t" \
    "s_nop 7\n\t" \
    EP("v0",  "v16", "v32") EP("v1",  "v17", "v33") \
    EP("v2",  "v18", "v34") EP("v3",  "v19", "v35") \
    EP("v4",  "v20", "v36") EP("v5",  "v21", "v37") \
    EP("v6",  "v22", "v38") EP("v7",  "v23", "v39") \
    EP("v8",  "v24", "v40") EP("v9",  "v25", "v41") \
    EP("v10", "v26", "v42") EP("v11", "v27", "v43") \
    EP("v12", "v28", "v44") EP("v13", "v29", "v45") \
    EP("v14", "v30", "v46") EP("v15", "v31", "v47") \
    "v_add_u32 v66, 64, v66\n\t"

// Pair with current operands in fbA (v48-55), prefetch next pair into fbB.
#define PAIR_A(P0, P1) \
    "ds_read_b128 v[56:59], v68 offset:" P0 "\n\t" \
    "ds_read_b128 v[60:63], v68 offset:" P1 "\n\t" \
    "s_waitcnt lgkmcnt(2)\n\t" \
    "v_mfma_f32_32x32x16_bf16 v[0:15], %[fa], v[48:51], %[fz]\n\t" \
    "v_mfma_f32_32x32x16_bf16 v[16:31], %[fa], v[52:55], %[fz]\n\t" \
    EPILOGUE

// Pair with current operands in fbB (v56-63), prefetch next pair into fbA.
#define PAIR_B(P0, P1) \
    "ds_read_b128 v[48:51], v68 offset:" P0 "\n\t" \
    "ds_read_b128 v[52:55], v68 offset:" P1 "\n\t" \
    "s_waitcnt lgkmcnt(2)\n\t" \
    "v_mfma_f32_32x32x16_bf16 v[0:15], %[fa], v[56:59], %[fz]\n\t" \
    "v_mfma_f32_32x32x16_bf16 v[16:31], %[fa], v[60:63], %[fz]\n\t" \
    EPILOGUE

// Last pair (current in fbB), nothing left to prefetch.
#define PAIR_B_LAST \
    "s_waitcnt lgkmcnt(0)\n\t" \
    "v_mfma_f32_32x32x16_bf16 v[0:15], %[fa], v[56:59], %[fz]\n\t" \
    "v_mfma_f32_32x32x16_bf16 v[16:31], %[fa], v[60:63], %[fz]\n\t" \
    EPILOGUE

// ---------------------------------------------------------------------------
// 1-NN on the matrix pipe: r14's pipelined mega-asm + ASYNC LDS STAGING.
// r14's books: block lifetime ~16.7k cyc (occupancy 32% x 43.5us / 16
// blocks/CU) vs ~3.2k cyc of asm compute -- the overhead is the staging
// loop's 8 serialized global->VGPR->LDS round-trips (register-starved by
// the v0-v68 clobber, the compiler emits load;vmcnt(0);ds_write per elem).
// global_load_lds (width 16, zero VGPRs, all 8 DMAs in flight) removes it.
// LDS dst is wave-uniform base + lane*16 -- matches our layout exactly:
// lane L of wave w, chunk k -> sb[k*TPB + w*64 + L].
// Asm layout: v[0:15]=d0 v[16:31]=d1 v[32:47]=best v48-63=fbA/fbB
// v64/v65=k0/k1 v66=vf v67=vf+32 v68=lds addr.
// C/D layout verified r4-r14 (absmax 0.0):
//   col(face)=lane&31, row(point)=(reg&3)+8*(reg>>2)+4*(lane>>5).
// key = (bits(dist^2+BIAS) & 0xFFFFC000) | face_idx; cross-slice atomicMin.
// ---------------------------------------------------------------------------
__global__ __launch_bounds__(TPB) void nn_kernel(
        const uint4* __restrict__ a_frags,
        const uint4* __restrict__ b_frags,
        unsigned* __restrict__ keys) {
    const int pg = blockIdx.x, sl = blockIdx.y, b = blockIdx.z;
    const int tid = threadIdx.x, wave = tid >> 6, lane = tid & 63;

    __shared__ uint4 sb[SL_TILES * 64];        // 32 KB

    // one 32-point A-tile per wave
    const int pt_tile = pg * 4 + wave;
    FragU a;
    a.u = a_frags[((size_t)(b * PT_TILES + pt_tile)) * 64 + lane];

    // async DMA stage of the whole 32-tile slice (no VGPR round-trip)
    const uint4* gsrc = b_frags + ((size_t)(b * FC_TILES + sl * SL_TILES)) * 64;
#pragma unroll
    for (int k = 0; k < (SL_TILES * 64) / TPB; ++k) {
        __builtin_amdgcn_global_load_lds(
            (const __attribute__((address_space(1))) unsigned int*)(const void*)(gsrc + k * TPB + tid),
            (__attribute__((address_space(3))) unsigned int*)(void*)&sb[k * TPB + (wave << 6)],
            16, 0, 0);
    }
    __syncthreads();   // compiler emits vmcnt(0) drain before s_barrier

    const floatx16 zero = {0.f, 0.f, 0.f, 0.f, 0.f, 0.f, 0.f, 0.f,
                           0.f, 0.f, 0.f, 0.f, 0.f, 0.f, 0.f, 0.f};
    const unsigned mask = 0xFFFFC000u;
    const unsigned vf_base = (unsigned)(sl * (SL_TILES * 32) + (lane & 31));
    // shared aperture is 2^48-aligned -> low 32 bits of the flat address are
    // the LDS segment offset.
    const unsigned lds_base = (unsigned)(unsigned long long)&sb[lane];

    unsigned b0, b1, b2, b3, b4, b5, b6, b7, b8, b9, b10, b11, b12, b13, b14, b15;
    asm volatile(
        "v_mov_b32 v68, %[lb]\n\t"
        "v_mov_b32 v66, %[vfb]\n\t"
        "v_mov_b32 v32, -1\n\t" "v_mov_b32 v33, -1\n\t"
        "v_mov_b32 v34, -1\n\t" "v_mov_b32 v35, -1\n\t"
        "v_mov_b32 v36, -1\n\t" "v_mov_b32 v37, -1\n\t"
        "v_mov_b32 v38, -1\n\t" "v_mov_b32 v39, -1\n\t"
        "v_mov_b32 v40, -1\n\t" "v_mov_b32 v41, -1\n\t"
        "v_mov_b32 v42, -1\n\t" "v_mov_b32 v43, -1\n\t"
        "v_mov_b32 v44, -1\n\t" "v_mov_b32 v45, -1\n\t"
        "v_mov_b32 v46, -1\n\t" "v_mov_b32 v47, -1\n\t"
        // preload pair 0 into fbA
        "ds_read_b128 v[48:51], v68 offset:0\n\t"
        "ds_read_b128 v[52:55], v68 offset:1024\n\t"
        PAIR_A("2048",  "3072")     // pair 0  (prefetch pair 1)
        PAIR_B("4096",  "5120")     // pair 1  (prefetch pair 2)
        PAIR_A("6144",  "7168")
        PAIR_B("8192",  "9216")
        PAIR_A("10240", "11264")
        PAIR_B("12288", "13312")
        PAIR_A("14336", "15360")
        PAIR_B("16384", "17408")
        PAIR_A("18432", "19456")
        PAIR_B("20480", "21504")
        PAIR_A("22528", "23552")
        PAIR_B("24576", "25600")
        PAIR_A("26624", "27648")
        PAIR_B("28672", "29696")
        PAIR_A("30720", "31744")    // pair 14 (prefetch pair 15)
        PAIR_B_LAST                 // pair 15
        "v_mov_b32 %0, v32\n\t"  "v_mov_b32 %1, v33\n\t"
        "v_mov_b32 %2, v34\n\t"  "v_mov_b32 %3, v35\n\t"
        "v_mov_b32 %4, v36\n\t"  "v_mov_b32 %5, v37\n\t"
        "v_mov_b32 %6, v38\n\t"  "v_mov_b32 %7, v39\n\t"
        "v_mov_b32 %8, v40\n\t"  "v_mov_b32 %9, v41\n\t"
        "v_mov_b32 %10, v42\n\t" "v_mov_b32 %11, v43\n\t"
        "v_mov_b32 %12, v44\n\t" "v_mov_b32 %13, v45\n\t"
        "v_mov_b32 %14, v46\n\t" "v_mov_b32 %15, v47"
        : "=v"(b0), "=v"(b1), "=v"(b2), "=v"(b3),
          "=v"(b4), "=v"(b5), "=v"(b6), "=v"(b7),
          "=v"(b8), "=v"(b9), "=v"(b10), "=v"(b11),
          "=v"(b12), "=v"(b13), "=v"(b14), "=v"(b15)
        : [fa]"v"(a.s), [fz]"v"(zero), [m]"s"(mask),
          [vfb]"v"(vf_base), [lb]"v"(lds_base)
        : "v0","v1","v2","v3","v4","v5","v6","v7",
          "v8","v9","v10","v11","v12","v13","v14","v15",
          "v16","v17","v18","v19","v20","v21","v22","v23",
          "v24","v25","v26","v27","v28","v29","v30","v31",
          "v32","v33","v34","v35","v36","v37","v38","v39",
          "v40","v41","v42","v43","v44","v45","v46","v47",
          "v48","v49","v50","v51","v52","v53","v54","v55",
          "v56","v57","v58","v59","v60","v61","v62","v63",
          "v64","v65","v66","v67","v68","memory");

    unsigned best[16] = {b0, b1, b2, b3, b4, b5, b6, b7,
                         b8, b9, b10, b11, b12, b13, b14, b15};

    // min across the 32 face-columns (stays within each 32-lane half)
#pragma unroll
    for (int e = 0; e < 16; ++e) {
        unsigned v = best[e];
#pragma unroll
        for (int m = 1; m < 32; m <<= 1)
            v = min(v, (unsigned)__shfl_xor((int)v, m, 64));
        best[e] = v;
    }
    unsigned* kb = keys + b * NP;
    if ((lane & 31) == 0) {
        int half = lane >> 5;
#pragma unroll
        for (int r = 0; r < 16; ++r) {
            int row = (r & 3) + 8 * (r >> 2) + 4 * half;
            atomicMin(&kb[pt_tile * 32 + row], best[r]);
        }
    }
}

// ---------------------------------------------------------------------------
// Per-point signed plane distance -> interp^3 sum + hit count; the LAST of
// the 128 blocks (device ticket) writes d_out. Fence cost is trivial here.
// ---------------------------------------------------------------------------
__global__ __launch_bounds__(TPB) void finalize_kernel(
        const float* __restrict__ pred,
        const float4* __restrict__ centers4,
        const float4* __restrict__ normals4,
        const unsigned int* __restrict__ keys,
        float* __restrict__ acc,
        unsigned* __restrict__ tk,
        float* __restrict__ out,
        int nblocks) {
    int i = blockIdx.x * blockDim.x + threadIdx.x;   // 0 .. B*N-1
    float val = 0.0f, cnt = 0.0f;
    if (i < NB * NP) {
        int b = i / NP;
        unsigned key = keys[i];
        int idx = (int)(key & (unsigned)(NF - 1));
        float4 c  = centers4[b * NF + idx];
        float4 nr = normals4[b * NF + idx];
        const float* pp = pred + (size_t)i * 3;
        float dx = pp[0] - c.x, dy = pp[1] - c.y, dz = pp[2] - c.z;
        float dist = dx * nr.x + dy * nr.y + dz * nr.z;
        float t = F_EPS - dist;
        if (t > 0.0f) { cnt = 1.0f; val = t * t * t; }
    }
    for (int off = 32; off > 0; off >>= 1) {
        val += __shfl_down(val, off, 64);
        cnt += __shfl_down(cnt, off, 64);
    }
    __shared__ float sv[TPB / 64], sn[TPB / 64];
    __shared__ unsigned s_tkt;
    int lane = threadIdx.x & 63, wave = threadIdx.x >> 6;
    if (lane == 0) { sv[wave] = val; sn[wave] = cnt; }
    __syncthreads();
    if (threadIdx.x == 0) {
        float v = 0.0f, cc = 0.0f;
#pragma unroll
        for (int w = 0; w < TPB / 64; ++w) { v += sv[w]; cc += sn[w]; }
        atomicAdd(&acc[0], v);
        atomicAdd(&acc[1], cc);
        __threadfence();
        s_tkt = atomicAdd(&tk[0], 1u);
        if (s_tkt == (unsigned)(nblocks - 1)) {      // last block writes out
            float a0 = __hip_atomic_load(&acc[0], __ATOMIC_RELAXED, __HIP_MEMORY_SCOPE_AGENT);
            float a1 = __hip_atomic_load(&acc[1], __ATOMIC_RELAXED, __HIP_MEMORY_SCOPE_AGENT);
            out[0] = a0 * (F_WEIGHT / (float)NB);
            out[1] = a1 * (1.0f / (float)(NB * NP));
        }
    }
}

extern "C" void kernel_launch(void* const* d_in, const int* in_sizes, int n_in,
                              void* d_out, int out_size, void* d_ws, size_t ws_size,
                              hipStream_t stream) {
    const float* pred  = (const float*)d_in[0];   // [B,N,3] f32
    const float* opos  = (const float*)d_in[1];   // [B,V,3] f32
    const int*   faces = (const int*)  d_in[2];   // [B,F,3] i32

    char* ws = (char*)d_ws;
    const size_t a_bytes = (size_t)NB * PT_TILES * 64 * 16;   // 1 MiB
    const size_t b_bytes = (size_t)NB * FC_TILES * 64 * 16;   // 2 MiB
    const size_t c_bytes = (size_t)NB * NF * 16;              // 1 MiB
    const size_t k_bytes = (size_t)NB * NP * sizeof(unsigned);// 128 KiB

    uint4*    a_frags  = (uint4*)ws;
    uint4*    b_frags  = (uint4*)(ws + a_bytes);
    float4*   centers4 = (float4*)(ws + a_bytes + b_bytes);
    float4*   normals4 = (float4*)(ws + a_bytes + b_bytes + c_bytes);
    unsigned* keys     = (unsigned*)(ws + a_bytes + b_bytes + 2 * c_bytes);
    float*    acc      = (float*)(ws + a_bytes + b_bytes + 2 * c_bytes + k_bytes);
    unsigned* tk       = (unsigned*)(ws + a_bytes + b_bytes + 2 * c_bytes + k_bytes + 64);

    prep_kernel<<<(NB * NF + TPB - 1) / TPB, TPB, 0, stream>>>(
        pred, opos, faces, a_frags, b_frags, centers4, normals4, keys, acc, tk);

    nn_kernel<<<dim3(PGB, FS, NB), TPB, 0, stream>>>(a_frags, b_frags, keys);

    int fin_blocks = (NB * NP + TPB - 1) / TPB;
    finalize_kernel<<<fin_blocks, TPB, 0, stream>>>(
        pred, centers4, normals4, keys, acc, tk, (float*)d_out, fin_blocks);
}